// Round 5
// baseline (422.523 us; speedup 1.0000x reference)
//
#include <hip/hip_runtime.h>
#include <math.h>

#define WIDTH   512
#define NPLANE  48          // 16 batch * 3 channels
#define TILE    32
#define HALO    5
#define NROWS   42          // TILE + 2*HALO
#define SSTR    52          // staged input row stride (words): 48 cols + 4 pad
#define HBS     48          // hb per-column slot count
#define GRIDX   16
#define NBLOCKS (GRIDX*GRIDX*NPLANE)
#define NPIX    (16.0*3.0*512.0*512.0)

struct GaussW { float w[11]; };

// staging tiles and transposed h-blur buffer share LDS (overlay, separated
// by a barrier): s = 17472 B, hb = 30720 B -> union 30720 B -> 5 blocks/CU
union SU {
    float s[2][NROWS][SSTR];
    float hb[5 * 32 * HBS];   // [q][col][(row + 4*(col&7)) % 48]
};

__device__ __forceinline__ void blur16(const float* vin, const GaussW& gw, float* o)
{
    #pragma unroll
    for (int t = 0; t < 16; ++t) {
        float s = vin[t] * gw.w[0];
        #pragma unroll
        for (int k = 1; k < 11; ++k) s = fmaf(gw.w[k], vin[t + k], s);
        o[t] = s;
    }
}

__global__ __launch_bounds__(256, 4)
void ssim_tile_kernel(const float* __restrict__ img1,
                      const float* __restrict__ img2,
                      float* __restrict__ partial,
                      unsigned int* __restrict__ counter,
                      float* __restrict__ out, GaussW gw)
{
    __shared__ __align__(16) SU su;
    __shared__ float red[4];
    __shared__ int isLast;

    const int tid = threadIdx.x;
    const int bx = blockIdx.x, by = blockIdx.y, bz = blockIdx.z;
    const float* __restrict__ p1 = img1 + (size_t)bz * (WIDTH * WIDTH);
    const float* __restrict__ p2 = img2 + (size_t)bz * (WIDTH * WIDTH);
    const int gx0 = bx * TILE - 8;      // first staged col (float4-aligned)
    const int gy0 = by * TILE - HALO;   // first staged row

    const bool interior = ((unsigned)(bx - 1) < 14u) & ((unsigned)(by - 1) < 14u);

    // ---- stage: 2 imgs x 42 rows x 12 float4 = 1008 vector loads ----
    if (interior) {
        #pragma unroll
        for (int k = 0; k < 4; ++k) {
            int l = tid + (k << 8);
            if (l < 1008) {
                int img = l >= 504;
                int u2  = img ? l - 504 : l;
                int r   = u2 / 12;
                int p   = u2 - r * 12;
                const float* gp = (img ? p2 : p1) + (gy0 + r) * WIDTH + (gx0 + (p << 2));
                *(float4*)&su.s[img][r][p << 2] = *(const float4*)gp;
            }
        }
    } else {
        #pragma unroll
        for (int k = 0; k < 4; ++k) {
            int l = tid + (k << 8);
            if (l < 1008) {
                int img = l >= 504;
                int u2  = img ? l - 504 : l;
                int r   = u2 / 12;
                int p   = u2 - r * 12;
                int gr = gy0 + r, gc = gx0 + (p << 2);
                float4 v = make_float4(0.f, 0.f, 0.f, 0.f);
                if ((unsigned)gr < WIDTH && (unsigned)gc <= (WIDTH - 4))
                    v = *(const float4*)((img ? p2 : p1) + gr * WIDTH + gc);
                *(float4*)&su.s[img][r][p << 2] = v;
            }
        }
    }
    __syncthreads();

    // ---- ONE horizontal pass; g wave-uniform by tid range ----
    // [0,84): img1 -> q0 (mu1h), q2 (s11h); [84,168): img2 -> q1, q3;
    // [168,252): cross -> q4
    const bool active = tid < 252;
    float oa[16], ob[16];
    int qa = 0, qb = 0, r = 0, c0 = 0, g = 0;
    if (active) {
        g = (tid >= 84) + (tid >= 168);
        int u2 = tid - g * 84;
        r  = u2 >> 1;
        c0 = (u2 & 1) << 4;
        float ld[32];
        if (g < 2) {
            const float* sp = &su.s[g][r][c0];
            #pragma unroll
            for (int p = 0; p < 8; ++p) {
                float4 v = *(const float4*)(sp + (p << 2));
                ld[4*p] = v.x; ld[4*p+1] = v.y; ld[4*p+2] = v.z; ld[4*p+3] = v.w;
            }
            blur16(ld + 3, gw, oa);
            #pragma unroll
            for (int i = 0; i < 26; ++i) ld[3 + i] *= ld[3 + i];
            blur16(ld + 3, gw, ob);
            qa = g; qb = g + 2;
        } else {
            float lb[32];
            const float* spa = &su.s[0][r][c0];
            const float* spb = &su.s[1][r][c0];
            #pragma unroll
            for (int p = 0; p < 8; ++p) {
                float4 v = *(const float4*)(spa + (p << 2));
                ld[4*p] = v.x; ld[4*p+1] = v.y; ld[4*p+2] = v.z; ld[4*p+3] = v.w;
                float4 w2 = *(const float4*)(spb + (p << 2));
                lb[4*p] = w2.x; lb[4*p+1] = w2.y; lb[4*p+2] = w2.z; lb[4*p+3] = w2.w;
            }
            #pragma unroll
            for (int i = 0; i < 26; ++i) ld[3 + i] *= lb[3 + i];
            blur16(ld + 3, gw, oa);
            qa = 4;
        }
    }
    __syncthreads();   // all staging reads done -> hb may overwrite s

    if (active) {
        #pragma unroll
        for (int j = 0; j < 16; ++j) {
            int col  = c0 + j;
            int slot = r + ((col & 7) << 2);
            if (slot >= HBS) slot -= HBS;
            su.hb[(qa * 32 + col) * HBS + slot] = oa[j];
        }
        if (g < 2) {
            #pragma unroll
            for (int j = 0; j < 16; ++j) {
                int col  = c0 + j;
                int slot = r + ((col & 7) << 2);
                if (slot >= HBS) slot -= HBS;
                su.hb[(qb * 32 + col) * HBS + slot] = ob[j];
            }
        }
    }
    __syncthreads();

    // ---- vertical pass: thread = (col c, rows r0..r0+3), all 5 q, b128 reads ----
    const int c  = tid & 31;
    const int r0 = (tid >> 5) << 2;
    const int R  = (c & 7) << 2;          // rotation for this column
    float acc[5][4];
    #pragma unroll
    for (int q = 0; q < 5; ++q) {
        const int base = (q * 32 + c) * HBS;
        float win[16];
        #pragma unroll
        for (int k = 0; k < 4; ++k) {
            int s0 = r0 + (k << 2) + R;
            if (s0 >= HBS) s0 -= HBS;
            float4 v = *(const float4*)&su.hb[base + s0];
            win[4*k] = v.x; win[4*k+1] = v.y; win[4*k+2] = v.z; win[4*k+3] = v.w;
        }
        #pragma unroll
        for (int i = 0; i < 4; ++i) {
            float s = win[i] * gw.w[0];
            #pragma unroll
            for (int k = 1; k < 11; ++k) s = fmaf(gw.w[k], win[i + k], s);
            acc[q][i] = s;
        }
    }

    // ---- SSIM map + block reduction ----
    const float C1 = 0.01f * 0.01f, C2 = 0.03f * 0.03f;
    float ssum = 0.f;
    #pragma unroll
    for (int i = 0; i < 4; ++i) {
        float a = acc[0][i], b = acc[1][i];
        float ab = a * b, a2 = a * a, b2 = b * b;
        float s11 = acc[2][i] - a2;
        float s22 = acc[3][i] - b2;
        float s12 = acc[4][i] - ab;
        float num = (2.f * ab + C1) * (2.f * s12 + C2);
        float den = (a2 + b2 + C1) * (s11 + s22 + C2);
        ssum += num / den;
    }

    #pragma unroll
    for (int off = 32; off > 0; off >>= 1) ssum += __shfl_down(ssum, off);
    if ((tid & 63) == 0) red[tid >> 6] = ssum;
    __syncthreads();

    // ---- last-block-done final reduction (deterministic order) ----
    if (tid == 0) {
        int bid = bx + GRIDX * (by + GRIDX * bz);
        float bsum = red[0] + red[1] + red[2] + red[3];
        __hip_atomic_store(&partial[bid], bsum, __ATOMIC_RELAXED,
                           __HIP_MEMORY_SCOPE_AGENT);
        unsigned int old = __hip_atomic_fetch_add(counter, 1u, __ATOMIC_ACQ_REL,
                                                  __HIP_MEMORY_SCOPE_AGENT);
        isLast = (old == (unsigned)(NBLOCKS - 1));
    }
    __syncthreads();

    if (isLast) {
        double s = 0.0;
        for (int i = tid; i < NBLOCKS; i += 256)
            s += (double)__hip_atomic_load(&partial[i], __ATOMIC_RELAXED,
                                           __HIP_MEMORY_SCOPE_AGENT);
        #pragma unroll
        for (int off = 32; off > 0; off >>= 1) s += __shfl_down(s, off);
        __shared__ double dred[4];
        if ((tid & 63) == 0) dred[tid >> 6] = s;
        __syncthreads();
        if (tid == 0)
            out[0] = (float)((dred[0] + dred[1] + dred[2] + dred[3]) / NPIX);
    }
}

extern "C" void kernel_launch(void* const* d_in, const int* in_sizes, int n_in,
                              void* d_out, int out_size, void* d_ws, size_t ws_size,
                              hipStream_t stream)
{
    GaussW gw;
    double g[11], sum = 0.0;
    for (int i = 0; i < 11; ++i) {
        double x = (double)(i - 5);
        g[i] = exp(-(x * x) / 4.5);
        sum += g[i];
    }
    for (int i = 0; i < 11; ++i) gw.w[i] = (float)(g[i] / sum);

    const float* img1 = (const float*)d_in[0];
    const float* img2 = (const float*)d_in[1];
    unsigned int* counter = (unsigned int*)d_ws;            // [0]: arrival counter
    float* partial = (float*)((char*)d_ws + 16);            // NBLOCKS floats
    float* out = (float*)d_out;

    // zero only the counter; every partial slot is written each launch
    hipMemsetAsync(d_ws, 0, 16, stream);

    dim3 grid(GRIDX, GRIDX, NPLANE);
    hipLaunchKernelGGL(ssim_tile_kernel, grid, dim3(256), 0, stream,
                       img1, img2, partial, counter, out, gw);
}

// Round 7
// 179.619 us; speedup vs baseline: 2.3523x; 2.3523x over previous
//
#include <hip/hip_runtime.h>
#include <math.h>

#define WIDTH   512
#define NPLANE  48          // 16 batch * 3 channels
#define TILE    32
#define HALO    5
#define NROWS   42          // TILE + 2*HALO
#define SSTR    52          // staged input row stride (words): 48 cols + 4 pad
#define HBS     44          // hb per-column slot count (44%32=12 -> banks spread)
#define GRIDX   16
#define NBLOCKS (GRIDX*GRIDX*NPLANE)
#define NPIX    (16.0*3.0*512.0*512.0)

struct GaussW { float w[11]; };

// staging tiles and transposed h-blur buffer share LDS (overlay, separated
// by a barrier): s = 17472 B, hb = 28160 B -> union 28160 B -> 5 blocks/CU
union SU {
    float s[2][NROWS][SSTR];
    float hb[5 * 32 * HBS];   // [q][col][row], col stride 44 words
};

__device__ __forceinline__ void blur16(const float* vin, const GaussW& gw, float* o)
{
    #pragma unroll
    for (int t = 0; t < 16; ++t) {
        float s = vin[t] * gw.w[0];
        #pragma unroll
        for (int k = 1; k < 11; ++k) s = fmaf(gw.w[k], vin[t + k], s);
        o[t] = s;
    }
}

__global__ __launch_bounds__(256, 5)
void ssim_tile_kernel(const float* __restrict__ img1,
                      const float* __restrict__ img2,
                      float* __restrict__ partial, GaussW gw)
{
    __shared__ __align__(16) SU su;
    __shared__ float red[4];

    const int tid = threadIdx.x;
    const int bx = blockIdx.x, by = blockIdx.y, bz = blockIdx.z;
    const float* __restrict__ p1 = img1 + (size_t)bz * (WIDTH * WIDTH);
    const float* __restrict__ p2 = img2 + (size_t)bz * (WIDTH * WIDTH);
    const int gx0 = bx * TILE - 8;      // first staged col (float4-aligned)
    const int gy0 = by * TILE - HALO;   // first staged row

    const bool interior = ((unsigned)(bx - 1) < 14u) & ((unsigned)(by - 1) < 14u);

    // ---- stage: 2 imgs x 42 rows x 12 float4 = 1008 vector loads ----
    if (interior) {
        #pragma unroll
        for (int k = 0; k < 4; ++k) {
            int l = tid + (k << 8);
            if (l < 1008) {
                int img = l >= 504;
                int u2  = img ? l - 504 : l;
                int r   = u2 / 12;
                int p   = u2 - r * 12;
                const float* gp = (img ? p2 : p1) + (gy0 + r) * WIDTH + (gx0 + (p << 2));
                *(float4*)&su.s[img][r][p << 2] = *(const float4*)gp;
            }
        }
    } else {
        #pragma unroll
        for (int k = 0; k < 4; ++k) {
            int l = tid + (k << 8);
            if (l < 1008) {
                int img = l >= 504;
                int u2  = img ? l - 504 : l;
                int r   = u2 / 12;
                int p   = u2 - r * 12;
                int gr = gy0 + r, gc = gx0 + (p << 2);
                float4 v = make_float4(0.f, 0.f, 0.f, 0.f);
                if ((unsigned)gr < WIDTH && (unsigned)gc <= (WIDTH - 4))
                    v = *(const float4*)((img ? p2 : p1) + gr * WIDTH + gc);
                *(float4*)&su.s[img][r][p << 2] = v;
            }
        }
    }
    __syncthreads();

    // ---- ONE horizontal pass; g wave-uniform by tid range ----
    // [0,84): img1 -> q0 (mu1h), q2 (s11h); [84,168): img2 -> q1, q3;
    // [168,252): cross -> q4
    const bool active = tid < 252;
    float oa[16], ob[16];
    int qa = 0, qb = 0, r = 0, c0 = 0, g = 0;
    if (active) {
        g = (tid >= 84) + (tid >= 168);
        int u2 = tid - g * 84;
        r  = u2 >> 1;
        c0 = (u2 & 1) << 4;
        float ld[32];
        if (g < 2) {
            const float* sp = &su.s[g][r][c0];
            #pragma unroll
            for (int p = 0; p < 8; ++p) {
                float4 v = *(const float4*)(sp + (p << 2));
                ld[4*p] = v.x; ld[4*p+1] = v.y; ld[4*p+2] = v.z; ld[4*p+3] = v.w;
            }
            blur16(ld + 3, gw, oa);
            #pragma unroll
            for (int i = 0; i < 26; ++i) ld[3 + i] *= ld[3 + i];
            blur16(ld + 3, gw, ob);
            qa = g; qb = g + 2;
        } else {
            float lb[32];
            const float* spa = &su.s[0][r][c0];
            const float* spb = &su.s[1][r][c0];
            #pragma unroll
            for (int p = 0; p < 8; ++p) {
                float4 v = *(const float4*)(spa + (p << 2));
                ld[4*p] = v.x; ld[4*p+1] = v.y; ld[4*p+2] = v.z; ld[4*p+3] = v.w;
                float4 w2 = *(const float4*)(spb + (p << 2));
                lb[4*p] = w2.x; lb[4*p+1] = w2.y; lb[4*p+2] = w2.z; lb[4*p+3] = w2.w;
            }
            #pragma unroll
            for (int i = 0; i < 26; ++i) ld[3 + i] *= lb[3 + i];
            blur16(ld + 3, gw, oa);
            qa = 4;
        }
    }
    __syncthreads();   // all staging reads done -> hb may overwrite s

    if (active) {
        const int ba = qa * 32 + c0;
        #pragma unroll
        for (int j = 0; j < 16; ++j)
            su.hb[(ba + j) * HBS + r] = oa[j];
        if (g < 2) {
            const int bb = qb * 32 + c0;
            #pragma unroll
            for (int j = 0; j < 16; ++j)
                su.hb[(bb + j) * HBS + r] = ob[j];
        }
    }
    __syncthreads();

    // ---- vertical pass: thread = (col c, rows r0..r0+3), all 5 q, b128 reads ----
    const int c  = tid & 31;
    const int r0 = (tid >> 5) << 2;
    float acc[5][4];
    #pragma unroll
    for (int q = 0; q < 5; ++q) {
        const int base = (q * 32 + c) * HBS + r0;
        float win[16];
        #pragma unroll
        for (int k = 0; k < 4; ++k) {
            float4 v = *(const float4*)&su.hb[base + (k << 2)];
            win[4*k] = v.x; win[4*k+1] = v.y; win[4*k+2] = v.z; win[4*k+3] = v.w;
        }
        #pragma unroll
        for (int i = 0; i < 4; ++i) {
            float s = win[i] * gw.w[0];
            #pragma unroll
            for (int k = 1; k < 11; ++k) s = fmaf(gw.w[k], win[i + k], s);
            acc[q][i] = s;
        }
    }

    // ---- SSIM map + block reduction ----
    const float C1 = 0.01f * 0.01f, C2 = 0.03f * 0.03f;
    float ssum = 0.f;
    #pragma unroll
    for (int i = 0; i < 4; ++i) {
        float a = acc[0][i], b = acc[1][i];
        float ab = a * b, a2 = a * a, b2 = b * b;
        float s11 = acc[2][i] - a2;
        float s22 = acc[3][i] - b2;
        float s12 = acc[4][i] - ab;
        float num = (2.f * ab + C1) * (2.f * s12 + C2);
        float den = (a2 + b2 + C1) * (s11 + s22 + C2);
        ssum += num / den;
    }

    #pragma unroll
    for (int off = 32; off > 0; off >>= 1) ssum += __shfl_down(ssum, off);
    if ((tid & 63) == 0) red[tid >> 6] = ssum;
    __syncthreads();
    if (tid == 0)
        partial[bx + GRIDX * (by + GRIDX * bz)] = red[0] + red[1] + red[2] + red[3];
}

__global__ __launch_bounds__(1024)
void ssim_reduce_kernel(const float* __restrict__ partial, float* __restrict__ out)
{
    __shared__ double red[16];
    double s = 0.0;
    for (int i = threadIdx.x; i < NBLOCKS; i += 1024) s += (double)partial[i];
    #pragma unroll
    for (int off = 32; off > 0; off >>= 1) s += __shfl_down(s, off);
    if ((threadIdx.x & 63) == 0) red[threadIdx.x >> 6] = s;
    __syncthreads();
    if (threadIdx.x == 0) {
        double t = 0.0;
        #pragma unroll
        for (int w = 0; w < 16; ++w) t += red[w];
        out[0] = (float)(t / NPIX);
    }
}

extern "C" void kernel_launch(void* const* d_in, const int* in_sizes, int n_in,
                              void* d_out, int out_size, void* d_ws, size_t ws_size,
                              hipStream_t stream)
{
    GaussW gw;
    double g[11], sum = 0.0;
    for (int i = 0; i < 11; ++i) {
        double x = (double)(i - 5);
        g[i] = exp(-(x * x) / 4.5);
        sum += g[i];
    }
    for (int i = 0; i < 11; ++i) gw.w[i] = (float)(g[i] / sum);

    const float* img1 = (const float*)d_in[0];
    const float* img2 = (const float*)d_in[1];
    float* partial = (float*)d_ws;   // NBLOCKS floats; every slot written each launch
    float* out = (float*)d_out;

    dim3 grid(GRIDX, GRIDX, NPLANE);
    hipLaunchKernelGGL(ssim_tile_kernel, grid, dim3(256), 0, stream,
                       img1, img2, partial, gw);
    hipLaunchKernelGGL(ssim_reduce_kernel, dim3(1), dim3(1024), 0, stream,
                       partial, out);
}